// Round 1
// baseline (528.070 us; speedup 1.0000x reference)
//
#include <hip/hip_runtime.h>
#include <cstdint>

#define NB   64
#define ND   256
#define NHW  1024
#define NTOK 65536
#define NDC  128
#define NK   1024

#define OFF_LOSS 16777216
#define OFF_Q    16777217
#define OFF_PERP 16842753

#define GAPTHR 1e-3f
#define NEGINF (-3.402823466e38f)

__device__ __forceinline__ bool better(float s, int i, float s2, int i2) {
  return (s > s2) || (s == s2 && i < i2);
}

// insert (s,i) into sorted-desc top-4 (first-index wins ties)
__device__ __forceinline__ void ins4(float* bs, int* bi, float s, int i) {
  if (better(s, i, bs[3], bi[3])) {
    bs[3] = s; bi[3] = i;
    if (better(bs[3], bi[3], bs[2], bi[2])) { float t=bs[2]; bs[2]=bs[3]; bs[3]=t; int u=bi[2]; bi[2]=bi[3]; bi[3]=u; }
    if (better(bs[2], bi[2], bs[1], bi[1])) { float t=bs[1]; bs[1]=bs[2]; bs[2]=t; int u=bi[1]; bi[1]=bi[2]; bi[2]=u; }
    if (better(bs[1], bi[1], bs[0], bi[0])) { float t=bs[0]; bs[0]=bs[1]; bs[1]=t; int u=bi[0]; bi[0]=bi[1]; bi[1]=u; }
  }
}

// ---------- init: transposes, half-norms, zero accumulators ----------
__global__ __launch_bounds__(256) void k_init(
    const float* __restrict__ lut, const float* __restrict__ preW,
    const float* __restrict__ postW,
    float* __restrict__ lutT, float* __restrict__ preWT, float* __restrict__ postWT,
    float* __restrict__ halfn, int* __restrict__ counts, double* __restrict__ lossAcc) {
  int tid = blockIdx.x * 256 + threadIdx.x;
  int stride = gridDim.x * 256;
  for (int i = tid; i < NK * NDC; i += stride) {        // lut [K][DC] -> lutT[DC][K]
    int k = i / NDC, c = i % NDC;
    lutT[c * NK + k] = lut[i];
  }
  for (int i = tid; i < NDC * ND; i += stride) {        // preW [DC][D] -> preWT[D][DC]
    int o = i / ND, c = i % ND;
    preWT[c * NDC + o] = preW[i];
  }
  for (int i = tid; i < ND * NDC; i += stride) {        // postW [D][DC] -> postWT[DC][D]
    int o = i / NDC, c = i % NDC;
    postWT[c * ND + o] = postW[i];
  }
  if (tid < NK) {
    float s = 0.f;
    for (int c = 0; c < NDC; c++) { float v = lut[tid * NDC + c]; s = fmaf(v, v, s); }
    halfn[tid] = 0.5f * s;
    counts[tid] = 0;
  }
  if (tid == 0) *lossAcc = 0.0;
}

// ---------- pre-conv: zf[n][o] = sum_c x[b][c][p] * preW[o][c] + pre_b[o] (f64-accurate) ----
__global__ __launch_bounds__(256) void k_preconv(
    const float* __restrict__ x, const float* __restrict__ preWT,
    const float* __restrict__ pre_b, float* __restrict__ zf) {
  __shared__ float Xs[16][64];
  __shared__ float Ws[16][64];
  int bx = blockIdx.x;                      // 2048 = 64 b * (16 ptile * 2 otile)
  int b = bx >> 5; int rem = bx & 31;
  int p0 = (rem >> 1) * 64; int o0 = (rem & 1) * 64;
  int tid = threadIdx.x;
  int tx = tid & 15, ty = tid >> 4;
  double acc[4][4];
  #pragma unroll
  for (int i = 0; i < 4; i++)
    #pragma unroll
    for (int j = 0; j < 4; j++) acc[i][j] = 0.0;
  const float* xb = x + (size_t)b * (ND * NHW);
  int sc = tid >> 4, sp = (tid & 15) * 4;
  for (int c0 = 0; c0 < ND; c0 += 16) {
    *reinterpret_cast<float4*>(&Xs[sc][sp]) =
        *reinterpret_cast<const float4*>(&xb[(c0 + sc) * NHW + p0 + sp]);
    *reinterpret_cast<float4*>(&Ws[sc][sp]) =
        *reinterpret_cast<const float4*>(&preWT[(c0 + sc) * NDC + o0 + sp]);
    __syncthreads();
    float c32[4][4];
    #pragma unroll
    for (int i = 0; i < 4; i++)
      #pragma unroll
      for (int j = 0; j < 4; j++) c32[i][j] = 0.f;
    #pragma unroll
    for (int k = 0; k < 16; k++) {
      float4 a = *reinterpret_cast<const float4*>(&Xs[k][tx * 4]);
      float4 w = *reinterpret_cast<const float4*>(&Ws[k][ty * 4]);
      float av[4] = {a.x, a.y, a.z, a.w};
      float wv[4] = {w.x, w.y, w.z, w.w};
      #pragma unroll
      for (int i = 0; i < 4; i++)
        #pragma unroll
        for (int j = 0; j < 4; j++) c32[i][j] = fmaf(av[i], wv[j], c32[i][j]);
    }
    #pragma unroll
    for (int i = 0; i < 4; i++)
      #pragma unroll
      for (int j = 0; j < 4; j++) acc[i][j] += (double)c32[i][j];
    __syncthreads();
  }
  float4 bb = *reinterpret_cast<const float4*>(&pre_b[o0 + ty * 4]);
  float bv[4] = {bb.x, bb.y, bb.z, bb.w};
  #pragma unroll
  for (int i = 0; i < 4; i++) {
    int p = p0 + tx * 4 + i;
    float4 v;
    v.x = (float)(acc[i][0] + (double)bv[0]);
    v.y = (float)(acc[i][1] + (double)bv[1]);
    v.z = (float)(acc[i][2] + (double)bv[2]);
    v.w = (float)(acc[i][3] + (double)bv[3]);
    *reinterpret_cast<float4*>(&zf[((size_t)b * NHW + p) * NDC + o0 + ty * 4]) = v;
  }
}

// ---------- distance: argmax_k (z.c - 0.5|c|^2) with top-4 + gap for rescoring ----------
__global__ __launch_bounds__(256) void k_dist(
    const float* __restrict__ zf, const float* __restrict__ lutT,
    const float* __restrict__ halfn,
    int* __restrict__ q, float* __restrict__ gap, int* __restrict__ cand) {
  __shared__ float Zt[128][64];     // 32 KB, transposed z tile (reused for merge)
  __shared__ float Ct[2][16][64];   // 8 KB, double-buffered code chunk
  __shared__ float Hn[NK];          // 4 KB
  int n0 = blockIdx.x * 64;
  int tid = threadIdx.x;
  int tx = tid & 15, ty = tid >> 4;
  for (int i = tid; i < NK; i += 256) Hn[i] = halfn[i];
  {
    int t = tid >> 2, cl = tid & 3;
    const float* zr = zf + (size_t)(n0 + t) * NDC;
    #pragma unroll
    for (int i = 0; i < 8; i++) {
      int c = cl * 4 + i * 16;
      float4 v = *reinterpret_cast<const float4*>(&zr[c]);
      Zt[c + 0][t] = v.x; Zt[c + 1][t] = v.y; Zt[c + 2][t] = v.z; Zt[c + 3][t] = v.w;
    }
  }
  float bs[4][4]; int bi[4][4];
  #pragma unroll
  for (int i = 0; i < 4; i++)
    #pragma unroll
    for (int s = 0; s < 4; s++) { bs[i][s] = NEGINF; bi[i][s] = 0x7fffffff; }
  int sci = tid >> 4, sk = (tid & 15) * 4;
  for (int kt = 0; kt < 16; kt++) {
    int code0 = kt * 64;
    float acc[4][4];
    #pragma unroll
    for (int i = 0; i < 4; i++)
      #pragma unroll
      for (int j = 0; j < 4; j++) acc[i][j] = 0.f;
    for (int cc = 0; cc < 8; cc++) {
      float* ctw = &Ct[cc & 1][0][0];
      *reinterpret_cast<float4*>(&ctw[sci * 64 + sk]) =
          *reinterpret_cast<const float4*>(&lutT[(cc * 16 + sci) * NK + code0 + sk]);
      __syncthreads();
      const float (*ctr)[64] = Ct[cc & 1];
      #pragma unroll
      for (int k = 0; k < 16; k++) {
        float4 a = *reinterpret_cast<const float4*>(&Zt[cc * 16 + k][tx * 4]);
        float4 w = *reinterpret_cast<const float4*>(&ctr[k][ty * 4]);
        float av[4] = {a.x, a.y, a.z, a.w};
        float wv[4] = {w.x, w.y, w.z, w.w};
        #pragma unroll
        for (int i = 0; i < 4; i++)
          #pragma unroll
          for (int j = 0; j < 4; j++) acc[i][j] = fmaf(av[i], wv[j], acc[i][j]);
      }
    }
    #pragma unroll
    for (int j = 0; j < 4; j++) {
      int idx = code0 + ty * 4 + j;
      float hn = Hn[idx];
      #pragma unroll
      for (int i = 0; i < 4; i++) ins4(bs[i], bi[i], acc[i][j] - hn, idx);
    }
  }
  __syncthreads();              // all Zt reads done; safe to reuse as merge buffer
  float* mS = &Zt[0][0];                        // [64 entries][64 tokens]
  int* mI = reinterpret_cast<int*>(&Zt[64][0]); // [64 entries][64 tokens]
  #pragma unroll
  for (int i = 0; i < 4; i++) {
    int t = tx * 4 + i;
    #pragma unroll
    for (int s = 0; s < 4; s++) {
      mS[(ty * 4 + s) * 64 + t] = bs[i][s];
      mI[(ty * 4 + s) * 64 + t] = bi[i][s];
    }
  }
  __syncthreads();
  if (tid < 64) {
    int t = tid;
    float fs[4]; int fi[4];
    #pragma unroll
    for (int s = 0; s < 4; s++) { fs[s] = NEGINF; fi[s] = 0x7fffffff; }
    for (int e = 0; e < 64; e++) ins4(fs, fi, mS[e * 64 + t], mI[e * 64 + t]);
    int n = n0 + t;
    q[n] = fi[0];
    gap[n] = fs[0] - fs[1];
    cand[4 * n + 0] = fi[0]; cand[4 * n + 1] = fi[1];
    cand[4 * n + 2] = fi[2]; cand[4 * n + 3] = fi[3];
  }
}

// ---------- f64 rescore of near-ties ----------
__global__ __launch_bounds__(256) void k_rescore(
    const float* __restrict__ zf, const float* __restrict__ lut,
    const float* __restrict__ gap, const int* __restrict__ cand, int* __restrict__ q) {
  int n = blockIdx.x * 256 + threadIdx.x;
  if (n >= NTOK) return;
  if (gap[n] >= GAPTHR) return;
  const float* zr = zf + (size_t)n * NDC;
  double best = 1e300; int bidx = 0x7fffffff;
  for (int e = 0; e < 4; e++) {
    int ci = cand[4 * n + e];
    const float* cr = lut + (size_t)ci * NDC;
    double d = 0.0;
    for (int c = 0; c < NDC; c++) {
      double diff = (double)zr[c] - (double)cr[c];
      d = fma(diff, diff, d);
    }
    if (d < best || (d == best && ci < bidx)) { best = d; bidx = ci; }
  }
  q[n] = bidx;
}

// ---------- histogram + q_map ----------
__global__ __launch_bounds__(256) void k_hist(
    const int* __restrict__ q, int* __restrict__ counts, float* __restrict__ outq) {
  int n = blockIdx.x * 256 + threadIdx.x;
  if (n >= NTOK) return;
  int c = q[n];
  atomicAdd(&counts[c], 1);
  outq[n] = (float)c;
}

// ---------- post-conv + loss: out[b][o][p] = sum_c xe[c]*postW[o][c] + post_b[o] ----------
__global__ __launch_bounds__(256) void k_post(
    const float* __restrict__ zf, const float* __restrict__ lut,
    const int* __restrict__ q, const float* __restrict__ postWT,
    const float* __restrict__ post_b, float* __restrict__ out,
    double* __restrict__ lossAcc) {
  __shared__ float XeT[128][64];    // 32 KB
  __shared__ float Wt[2][16][64];   // 8 KB
  __shared__ float red[256];
  int n0 = blockIdx.x * 64;
  int b = n0 >> 10; int p0 = n0 & 1023;
  int tid = threadIdx.x;
  int tx = tid & 15, ty = tid >> 4;
  float lpart = 0.f;
  {
    int t = tid >> 2, cl = tid & 3;
    int n = n0 + t;
    const float* cr = lut + (size_t)q[n] * NDC;
    const float* zr = zf + (size_t)n * NDC;
    #pragma unroll
    for (int i = 0; i < 8; i++) {
      int c = cl * 4 + i * 16;
      float4 xe = *reinterpret_cast<const float4*>(&cr[c]);
      float4 zz = *reinterpret_cast<const float4*>(&zr[c]);
      XeT[c + 0][t] = xe.x; XeT[c + 1][t] = xe.y; XeT[c + 2][t] = xe.z; XeT[c + 3][t] = xe.w;
      float d0 = zz.x - xe.x, d1 = zz.y - xe.y, d2 = zz.z - xe.z, d3 = zz.w - xe.w;
      lpart += d0 * d0 + d1 * d1 + d2 * d2 + d3 * d3;
    }
  }
  red[tid] = lpart;
  __syncthreads();
  for (int s = 128; s > 0; s >>= 1) {
    if (tid < s) red[tid] += red[tid + s];
    __syncthreads();
  }
  if (tid == 0) atomicAdd(lossAcc, (double)red[0]);
  int sci = tid >> 4, sk = (tid & 15) * 4;
  for (int ot = 0; ot < 4; ot++) {
    int o0 = ot * 64;
    float acc[4][4];
    #pragma unroll
    for (int i = 0; i < 4; i++)
      #pragma unroll
      for (int j = 0; j < 4; j++) acc[i][j] = 0.f;
    for (int cc = 0; cc < 8; cc++) {
      float* wtw = &Wt[cc & 1][0][0];
      *reinterpret_cast<float4*>(&wtw[sci * 64 + sk]) =
          *reinterpret_cast<const float4*>(&postWT[(cc * 16 + sci) * ND + o0 + sk]);
      __syncthreads();
      const float (*wtr)[64] = Wt[cc & 1];
      #pragma unroll
      for (int k = 0; k < 16; k++) {
        float4 a = *reinterpret_cast<const float4*>(&XeT[cc * 16 + k][tx * 4]);
        float4 w = *reinterpret_cast<const float4*>(&wtr[k][ty * 4]);
        float av[4] = {a.x, a.y, a.z, a.w};
        float wv[4] = {w.x, w.y, w.z, w.w};
        #pragma unroll
        for (int i = 0; i < 4; i++)
          #pragma unroll
          for (int j = 0; j < 4; j++) acc[i][j] = fmaf(av[i], wv[j], acc[i][j]);
      }
    }
    #pragma unroll
    for (int j = 0; j < 4; j++) {
      int o = o0 + ty * 4 + j;
      float bias = post_b[o];
      float4 v;
      v.x = acc[0][j] + bias; v.y = acc[1][j] + bias;
      v.z = acc[2][j] + bias; v.w = acc[3][j] + bias;
      *reinterpret_cast<float4*>(&out[((size_t)(b * ND + o)) * NHW + p0 + tx * 4]) = v;
    }
  }
}

// ---------- finalize: loss scalar + perplexity ----------
__global__ __launch_bounds__(256) void k_fin(
    const double* __restrict__ lossAcc, const int* __restrict__ counts,
    float* __restrict__ out_loss, float* __restrict__ out_perp) {
  __shared__ float red[256];
  int tid = threadIdx.x;
  float h = 0.f;
  for (int i = tid; i < NK; i += 256) {
    float e = (float)counts[i] * (1.0f / (float)NTOK);
    h += e * logf(e + 1e-10f);
  }
  red[tid] = h;
  __syncthreads();
  for (int s = 128; s > 0; s >>= 1) {
    if (tid < s) red[tid] += red[tid + s];
    __syncthreads();
  }
  if (tid == 0) {
    *out_perp = expf(-red[0]);
    *out_loss = (float)(*lossAcc / ((double)NTOK * (double)NDC));
  }
}

extern "C" void kernel_launch(void* const* d_in, const int* in_sizes, int n_in,
                              void* d_out, int out_size, void* d_ws, size_t ws_size,
                              hipStream_t stream) {
  const float* x     = (const float*)d_in[0];
  const float* preW  = (const float*)d_in[1];
  const float* preb  = (const float*)d_in[2];
  const float* postW = (const float*)d_in[3];
  const float* postb = (const float*)d_in[4];
  const float* lut   = (const float*)d_in[5];
  float* out = (float*)d_out;

  char* ws = (char*)d_ws;
  float*  zf      = (float*)(ws);                       // 33,554,432 B
  float*  lutT    = (float*)(ws + 33554432);            //    524,288 B
  float*  preWT   = (float*)(ws + 34078720);            //    131,072 B
  float*  postWT  = (float*)(ws + 34209792);            //    131,072 B
  float*  halfn   = (float*)(ws + 34340864);            //      4,096 B
  int*    q       = (int*)  (ws + 34344960);            //    262,144 B
  float*  gap     = (float*)(ws + 34607104);            //    262,144 B
  int*    cand    = (int*)  (ws + 34869248);            //  1,048,576 B
  int*    counts  = (int*)  (ws + 35917824);            //      4,096 B
  double* lossAcc = (double*)(ws + 35921920);           //          8 B

  float* out_loss = out + OFF_LOSS;
  float* out_q    = out + OFF_Q;
  float* out_perp = out + OFF_PERP;

  hipLaunchKernelGGL(k_init, dim3(512), dim3(256), 0, stream,
                     lut, preW, postW, lutT, preWT, postWT, halfn, counts, lossAcc);
  hipLaunchKernelGGL(k_preconv, dim3(2048), dim3(256), 0, stream, x, preWT, preb, zf);
  hipLaunchKernelGGL(k_dist, dim3(1024), dim3(256), 0, stream, zf, lutT, halfn, q, gap, cand);
  hipLaunchKernelGGL(k_rescore, dim3(256), dim3(256), 0, stream, zf, lut, gap, cand, q);
  hipLaunchKernelGGL(k_hist, dim3(256), dim3(256), 0, stream, q, counts, out_q);
  hipLaunchKernelGGL(k_post, dim3(1024), dim3(256), 0, stream, zf, lut, q, postWT, postb, out, lossAcc);
  hipLaunchKernelGGL(k_fin, dim3(1), dim3(256), 0, stream, lossAcc, counts, out_loss, out_perp);
}

// Round 2
// 291.401 us; speedup vs baseline: 1.8122x; 1.8122x over previous
//
#include <hip/hip_runtime.h>
#include <cstdint>

#define NB   64
#define ND   256
#define NHW  1024
#define NTOK 65536
#define NDC  128
#define NK   1024

#define OFF_LOSS 16777216
#define OFF_Q    16777217
#define OFF_PERP 16842753

#define GAPTHR 4e-3f
#define NEGINF (-3.402823466e38f)

typedef short short8 __attribute__((ext_vector_type(8)));
typedef float f32x4 __attribute__((ext_vector_type(4)));

__device__ __forceinline__ unsigned short f2bf(float f) {
  unsigned u = __float_as_uint(f);
  u += 0x7FFFu + ((u >> 16) & 1u);
  return (unsigned short)(u >> 16);
}
__device__ __forceinline__ float bf2f(unsigned short h) {
  return __uint_as_float(((unsigned)h) << 16);
}

__device__ __forceinline__ void gll16(const void* g, void* l) {
  __builtin_amdgcn_global_load_lds(
      (const __attribute__((address_space(1))) unsigned int*)g,
      (__attribute__((address_space(3))) unsigned int*)l, 16, 0, 0);
}

// ---------- init: bf16-split codebook, transposes, neg-half-norms, zero accumulators ----------
__global__ __launch_bounds__(256) void k_init(
    const float* __restrict__ lut, const float* __restrict__ preW,
    const float* __restrict__ postW,
    unsigned short* __restrict__ ch, float* __restrict__ preWT, float* __restrict__ postWT,
    float* __restrict__ nhn, int* __restrict__ counts, double* __restrict__ lossAcc,
    int* __restrict__ ctr) {
  int tid = blockIdx.x * 256 + threadIdx.x;
  int stride = gridDim.x * 256;
  for (int i = tid; i < NK * NDC; i += stride) {   // lut -> split bf16 ch[code][256]
    int code = i >> 7, c = i & 127;
    float f = lut[i];
    unsigned short h1 = f2bf(f);
    float r = f - bf2f(h1);
    ch[code * 256 + c] = h1;
    ch[code * 256 + 128 + c] = f2bf(r);
  }
  for (int i = tid; i < NDC * ND; i += stride) {   // preW [DC][D] -> preWT[D][DC]
    int o = i / ND, c = i % ND;
    preWT[c * NDC + o] = preW[i];
  }
  for (int i = tid; i < ND * NDC; i += stride) {   // postW [D][DC] -> postWT[DC][D]
    int o = i / NDC, c = i % NDC;
    postWT[c * ND + o] = postW[i];
  }
  if (tid < NK) {
    float s = 0.f;
    for (int c = 0; c < NDC; c++) { float v = lut[tid * NDC + c]; s = fmaf(v, v, s); }
    nhn[tid] = -0.5f * s;
    counts[tid] = 0;
  }
  if (tid == 0) { *lossAcc = 0.0; *ctr = 0; }
}

// ---------- pre-conv: zf[n][o] = sum_c x[b][c][p] * preW[o][c] + pre_b[o] (f64-accurate) ----
__global__ __launch_bounds__(256) void k_preconv(
    const float* __restrict__ x, const float* __restrict__ preWT,
    const float* __restrict__ pre_b, float* __restrict__ zf) {
  __shared__ float Xs[16][64];
  __shared__ float Ws[16][64];
  int bx = blockIdx.x;
  int b = bx >> 5; int rem = bx & 31;
  int p0 = (rem >> 1) * 64; int o0 = (rem & 1) * 64;
  int tid = threadIdx.x;
  int tx = tid & 15, ty = tid >> 4;
  double acc[4][4];
  #pragma unroll
  for (int i = 0; i < 4; i++)
    #pragma unroll
    for (int j = 0; j < 4; j++) acc[i][j] = 0.0;
  const float* xb = x + (size_t)b * (ND * NHW);
  int sc = tid >> 4, sp = (tid & 15) * 4;
  for (int c0 = 0; c0 < ND; c0 += 16) {
    *reinterpret_cast<float4*>(&Xs[sc][sp]) =
        *reinterpret_cast<const float4*>(&xb[(c0 + sc) * NHW + p0 + sp]);
    *reinterpret_cast<float4*>(&Ws[sc][sp]) =
        *reinterpret_cast<const float4*>(&preWT[(c0 + sc) * NDC + o0 + sp]);
    __syncthreads();
    float c32[4][4];
    #pragma unroll
    for (int i = 0; i < 4; i++)
      #pragma unroll
      for (int j = 0; j < 4; j++) c32[i][j] = 0.f;
    #pragma unroll
    for (int k = 0; k < 16; k++) {
      float4 a = *reinterpret_cast<const float4*>(&Xs[k][tx * 4]);
      float4 w = *reinterpret_cast<const float4*>(&Ws[k][ty * 4]);
      float av[4] = {a.x, a.y, a.z, a.w};
      float wv[4] = {w.x, w.y, w.z, w.w};
      #pragma unroll
      for (int i = 0; i < 4; i++)
        #pragma unroll
        for (int j = 0; j < 4; j++) c32[i][j] = fmaf(av[i], wv[j], c32[i][j]);
    }
    #pragma unroll
    for (int i = 0; i < 4; i++)
      #pragma unroll
      for (int j = 0; j < 4; j++) acc[i][j] += (double)c32[i][j];
    __syncthreads();
  }
  float4 bb = *reinterpret_cast<const float4*>(&pre_b[o0 + ty * 4]);
  float bv[4] = {bb.x, bb.y, bb.z, bb.w};
  #pragma unroll
  for (int i = 0; i < 4; i++) {
    int p = p0 + tx * 4 + i;
    float4 v;
    v.x = (float)(acc[i][0] + (double)bv[0]);
    v.y = (float)(acc[i][1] + (double)bv[1]);
    v.z = (float)(acc[i][2] + (double)bv[2]);
    v.w = (float)(acc[i][3] + (double)bv[3]);
    *reinterpret_cast<float4*>(&zf[((size_t)b * NHW + p) * NDC + o0 + ty * 4]) = v;
  }
}

// ---------- distance via bf16-split MFMA: argmax_k (z.c - 0.5|c|^2), flag near-ties ----------
__global__ __launch_bounds__(256, 2) void k_dist(
    const float* __restrict__ zf, const unsigned short* __restrict__ ch,
    const float* __restrict__ nhn,
    int* __restrict__ q, int* __restrict__ list, int* __restrict__ ctr) {
  __shared__ __align__(16) short chbuf[2][16384];   // 2 x 32 KB code chunk (swizzled image)
  __shared__ float HnLds[NK];                       // 4 KB (negated half-norms)
  int tid = threadIdx.x;
  int lane = tid & 63, w = tid >> 6;
  int g = lane >> 4;
  int n0 = blockIdx.x * 128;

  for (int i = tid; i < NK; i += 256) HnLds[i] = nhn[i];

  // A fragments: 32 tokens per wave, bf16-split in registers (z1 in [0..3], z2 in [4..7])
  short8 az[2][8];
  {
    int arow = lane & 15;
    #pragma unroll
    for (int rt = 0; rt < 2; ++rt) {
      const float* zr = zf + (size_t)(n0 + w * 32 + rt * 16 + arow) * NDC;
      #pragma unroll
      for (int f = 0; f < 4; ++f) {
        const float* p = zr + f * 32 + g * 8;
        float4 v0 = *reinterpret_cast<const float4*>(p);
        float4 v1 = *reinterpret_cast<const float4*>(p + 4);
        float vv[8] = {v0.x, v0.y, v0.z, v0.w, v1.x, v1.y, v1.z, v1.w};
        short8 hi, lo;
        #pragma unroll
        for (int j = 0; j < 8; ++j) {
          unsigned short h1 = f2bf(vv[j]);
          float r = vv[j] - bf2f(h1);
          hi[j] = (short)h1;
          lo[j] = (short)f2bf(r);
        }
        az[rt][f] = hi;
        az[rt][4 + f] = lo;
      }
    }
  }

  float best[2][4], sec[2][4];
  int bidx[2][4];
  #pragma unroll
  for (int rt = 0; rt < 2; ++rt)
    #pragma unroll
    for (int r = 0; r < 4; ++r) { best[rt][r] = NEGINF; sec[rt][r] = NEGINF; bidx[rt][r] = 0; }

  const char* chg = (const char*)ch;
  // stage chunk 0
  {
    const char* gb = chg + 0;
    #pragma unroll
    for (int rr = 0; rr < 8; ++rr) {
      int o = rr * 4096 + tid * 16;
      int so = o ^ (((o >> 9) & 7) << 4);
      gll16(gb + so, ((char*)&chbuf[0][0]) + o);
    }
  }
  asm volatile("s_waitcnt vmcnt(0)" ::: "memory");
  __syncthreads();

  int cur = 0;
  for (int chunk = 0; chunk < 16; ++chunk) {
    if (chunk < 15) {                         // prefetch next chunk into other buffer
      const char* gb = chg + (chunk + 1) * 32768;
      #pragma unroll
      for (int rr = 0; rr < 8; ++rr) {
        int o = rr * 4096 + tid * 16;
        int so = o ^ (((o >> 9) & 7) << 4);
        gll16(gb + so, ((char*)&chbuf[cur ^ 1][0]) + o);
      }
    }
    const char* cb = (const char*)&chbuf[cur][0];
    for (int ct = 0; ct < 4; ++ct) {
      int codeg = chunk * 64 + ct * 16 + (lane & 15);
      float nh = HnLds[codeg];
      short8 bc[8];
      #pragma unroll
      for (int f = 0; f < 8; ++f) {
        int byte = ((lane & 15) + ct * 16) * 512 + f * 64 + g * 16;
        byte ^= ((lane & 7) << 4);
        bc[f] = *reinterpret_cast<const short8*>(cb + byte);
      }
      f32x4 acc0 = {nh, nh, nh, nh};
      f32x4 acc1 = {nh, nh, nh, nh};
      #pragma unroll
      for (int j = 0; j < 4; ++j) {
        acc0 = __builtin_amdgcn_mfma_f32_16x16x32_bf16(az[0][j], bc[j], acc0, 0, 0, 0);
        acc1 = __builtin_amdgcn_mfma_f32_16x16x32_bf16(az[1][j], bc[j], acc1, 0, 0, 0);
        acc0 = __builtin_amdgcn_mfma_f32_16x16x32_bf16(az[0][j], bc[4 + j], acc0, 0, 0, 0);
        acc1 = __builtin_amdgcn_mfma_f32_16x16x32_bf16(az[1][j], bc[4 + j], acc1, 0, 0, 0);
        acc0 = __builtin_amdgcn_mfma_f32_16x16x32_bf16(az[0][4 + j], bc[j], acc0, 0, 0, 0);
        acc1 = __builtin_amdgcn_mfma_f32_16x16x32_bf16(az[1][4 + j], bc[j], acc1, 0, 0, 0);
      }
      #pragma unroll
      for (int r = 0; r < 4; ++r) {
        float s0 = acc0[r];
        bool t0 = s0 > best[0][r];
        bidx[0][r] = t0 ? codeg : bidx[0][r];
        sec[0][r] = fmaxf(sec[0][r], fminf(s0, best[0][r]));
        best[0][r] = fmaxf(s0, best[0][r]);
        float s1 = acc1[r];
        bool t1 = s1 > best[1][r];
        bidx[1][r] = t1 ? codeg : bidx[1][r];
        sec[1][r] = fmaxf(sec[1][r], fminf(s1, best[1][r]));
        best[1][r] = fmaxf(s1, best[1][r]);
      }
    }
    asm volatile("s_waitcnt vmcnt(0)" ::: "memory");
    __syncthreads();
    cur ^= 1;
  }

  // cross-lane merge over the 16 code-columns (lanes sharing g), then write
  #pragma unroll
  for (int rt = 0; rt < 2; ++rt) {
    #pragma unroll
    for (int r = 0; r < 4; ++r) {
      float b = best[rt][r];
      float s2 = sec[rt][r];
      int bi_ = bidx[rt][r];
      #pragma unroll
      for (int m = 1; m < 16; m <<= 1) {
        float ob = __shfl_xor(b, m, 64);
        float os = __shfl_xor(s2, m, 64);
        int oi = __shfl_xor(bi_, m, 64);
        float ns = fmaxf(fmaxf(s2, os), fminf(b, ob));
        bool take = (ob > b) || (ob == b && oi < bi_);
        b = take ? ob : b;
        bi_ = take ? oi : bi_;
        s2 = ns;
      }
      if ((lane & 15) == 0) {
        int token = n0 + w * 32 + rt * 16 + g * 4 + r;
        q[token] = bi_;
        if (b - s2 < GAPTHR) {
          int pos = atomicAdd(ctr, 1);
          list[pos] = token;
        }
      }
    }
  }
}

// ---------- f64 full-scan rescore of flagged tokens (one wave per token) ----------
__global__ __launch_bounds__(256) void k_rescore(
    const float* __restrict__ zf, const float* __restrict__ lut,
    const int* __restrict__ list, const int* __restrict__ ctr, int* __restrict__ q) {
  int lane = threadIdx.x & 63;
  int wid = (blockIdx.x * 256 + threadIdx.x) >> 6;
  int nwaves = gridDim.x * 4;
  int nf = *ctr;
  for (int i = wid; i < nf; i += nwaves) {
    int token = list[i];
    const float* zr = zf + (size_t)token * NDC;
    double bd = 1e300;
    int bc_ = 0x7fffffff;
    for (int c = lane; c < NK; c += 64) {
      const float* cr = lut + (size_t)c * NDC;
      double d = 0.0;
      for (int k = 0; k < NDC; k += 4) {
        float4 cz = *reinterpret_cast<const float4*>(cr + k);
        float4 zz = *reinterpret_cast<const float4*>(zr + k);
        double d0 = (double)zz.x - (double)cz.x;
        double d1 = (double)zz.y - (double)cz.y;
        double d2 = (double)zz.z - (double)cz.z;
        double d3 = (double)zz.w - (double)cz.w;
        d = fma(d0, d0, d); d = fma(d1, d1, d);
        d = fma(d2, d2, d); d = fma(d3, d3, d);
      }
      if (d < bd || (d == bd && c < bc_)) { bd = d; bc_ = c; }
    }
    #pragma unroll
    for (int m = 1; m < 64; m <<= 1) {
      double od = __shfl_xor(bd, m, 64);
      int oc = __shfl_xor(bc_, m, 64);
      if (od < bd || (od == bd && oc < bc_)) { bd = od; bc_ = oc; }
    }
    if (lane == 0) q[token] = bc_;
  }
}

// ---------- histogram + q_map ----------
__global__ __launch_bounds__(256) void k_hist(
    const int* __restrict__ q, int* __restrict__ counts, float* __restrict__ outq) {
  int n = blockIdx.x * 256 + threadIdx.x;
  if (n >= NTOK) return;
  int c = q[n];
  atomicAdd(&counts[c], 1);
  outq[n] = (float)c;
}

// ---------- post-conv + loss ----------
__global__ __launch_bounds__(256) void k_post(
    const float* __restrict__ zf, const float* __restrict__ lut,
    const int* __restrict__ q, const float* __restrict__ postWT,
    const float* __restrict__ post_b, float* __restrict__ out,
    double* __restrict__ lossAcc) {
  __shared__ float XeT[128][64];
  __shared__ float Wt[2][16][64];
  __shared__ float red[256];
  int n0 = blockIdx.x * 64;
  int b = n0 >> 10; int p0 = n0 & 1023;
  int tid = threadIdx.x;
  int tx = tid & 15, ty = tid >> 4;
  float lpart = 0.f;
  {
    int t = tid >> 2, cl = tid & 3;
    int n = n0 + t;
    const float* cr = lut + (size_t)q[n] * NDC;
    const float* zr = zf + (size_t)n * NDC;
    #pragma unroll
    for (int i = 0; i < 8; i++) {
      int c = cl * 4 + i * 16;
      float4 xe = *reinterpret_cast<const float4*>(&cr[c]);
      float4 zz = *reinterpret_cast<const float4*>(&zr[c]);
      XeT[c + 0][t] = xe.x; XeT[c + 1][t] = xe.y; XeT[c + 2][t] = xe.z; XeT[c + 3][t] = xe.w;
      float d0 = zz.x - xe.x, d1 = zz.y - xe.y, d2 = zz.z - xe.z, d3 = zz.w - xe.w;
      lpart += d0 * d0 + d1 * d1 + d2 * d2 + d3 * d3;
    }
  }
  red[tid] = lpart;
  __syncthreads();
  for (int s = 128; s > 0; s >>= 1) {
    if (tid < s) red[tid] += red[tid + s];
    __syncthreads();
  }
  if (tid == 0) atomicAdd(lossAcc, (double)red[0]);
  int sci = tid >> 4, sk = (tid & 15) * 4;
  for (int ot = 0; ot < 4; ot++) {
    int o0 = ot * 64;
    float acc[4][4];
    #pragma unroll
    for (int i = 0; i < 4; i++)
      #pragma unroll
      for (int j = 0; j < 4; j++) acc[i][j] = 0.f;
    for (int cc = 0; cc < 8; cc++) {
      float* wtw = &Wt[cc & 1][0][0];
      *reinterpret_cast<float4*>(&wtw[sci * 64 + sk]) =
          *reinterpret_cast<const float4*>(&postWT[(cc * 16 + sci) * ND + o0 + sk]);
      __syncthreads();
      const float (*wtr)[64] = Wt[cc & 1];
      #pragma unroll
      for (int k = 0; k < 16; k++) {
        float4 a = *reinterpret_cast<const float4*>(&XeT[cc * 16 + k][tx * 4]);
        float4 w = *reinterpret_cast<const float4*>(&wtr[k][ty * 4]);
        float av[4] = {a.x, a.y, a.z, a.w};
        float wv[4] = {w.x, w.y, w.z, w.w};
        #pragma unroll
        for (int i = 0; i < 4; i++)
          #pragma unroll
          for (int j = 0; j < 4; j++) acc[i][j] = fmaf(av[i], wv[j], acc[i][j]);
      }
    }
    #pragma unroll
    for (int j = 0; j < 4; j++) {
      int o = o0 + ty * 4 + j;
      float bias = post_b[o];
      float4 v;
      v.x = acc[0][j] + bias; v.y = acc[1][j] + bias;
      v.z = acc[2][j] + bias; v.w = acc[3][j] + bias;
      *reinterpret_cast<float4*>(&out[((size_t)(b * ND + o)) * NHW + p0 + tx * 4]) = v;
    }
  }
}

// ---------- finalize ----------
__global__ __launch_bounds__(256) void k_fin(
    const double* __restrict__ lossAcc, const int* __restrict__ counts,
    float* __restrict__ out_loss, float* __restrict__ out_perp) {
  __shared__ float red[256];
  int tid = threadIdx.x;
  float h = 0.f;
  for (int i = tid; i < NK; i += 256) {
    float e = (float)counts[i] * (1.0f / (float)NTOK);
    h += e * logf(e + 1e-10f);
  }
  red[tid] = h;
  __syncthreads();
  for (int s = 128; s > 0; s >>= 1) {
    if (tid < s) red[tid] += red[tid + s];
    __syncthreads();
  }
  if (tid == 0) {
    *out_perp = expf(-red[0]);
    *out_loss = (float)(*lossAcc / ((double)NTOK * (double)NDC));
  }
}

extern "C" void kernel_launch(void* const* d_in, const int* in_sizes, int n_in,
                              void* d_out, int out_size, void* d_ws, size_t ws_size,
                              hipStream_t stream) {
  const float* x     = (const float*)d_in[0];
  const float* preW  = (const float*)d_in[1];
  const float* preb  = (const float*)d_in[2];
  const float* postW = (const float*)d_in[3];
  const float* postb = (const float*)d_in[4];
  const float* lut   = (const float*)d_in[5];
  float* out = (float*)d_out;

  char* ws = (char*)d_ws;
  float*          zf      = (float*)(ws);                 // 33,554,432 B
  unsigned short* ch      = (unsigned short*)(ws + 33554432); // 524,288 B
  float*          preWT   = (float*)(ws + 34078720);      // 131,072 B
  float*          postWT  = (float*)(ws + 34209792);      // 131,072 B
  float*          nhn     = (float*)(ws + 34340864);      //   4,096 B
  int*            q       = (int*)  (ws + 34344960);      // 262,144 B
  int*            list    = (int*)  (ws + 34607104);      // 262,144 B
  int*            counts  = (int*)  (ws + 34869248);      //   4,096 B
  double*         lossAcc = (double*)(ws + 34873344);     //       8 B
  int*            ctr     = (int*)  (ws + 34873352);      //       4 B

  float* out_loss = out + OFF_LOSS;
  float* out_q    = out + OFF_Q;
  float* out_perp = out + OFF_PERP;

  hipLaunchKernelGGL(k_init, dim3(512), dim3(256), 0, stream,
                     lut, preW, postW, ch, preWT, postWT, nhn, counts, lossAcc, ctr);
  hipLaunchKernelGGL(k_preconv, dim3(2048), dim3(256), 0, stream, x, preWT, preb, zf);
  hipLaunchKernelGGL(k_dist, dim3(512), dim3(256), 0, stream, zf, ch, nhn, q, list, ctr);
  hipLaunchKernelGGL(k_rescore, dim3(256), dim3(256), 0, stream, zf, lut, list, ctr, q);
  hipLaunchKernelGGL(k_hist, dim3(256), dim3(256), 0, stream, q, counts, out_q);
  hipLaunchKernelGGL(k_post, dim3(1024), dim3(256), 0, stream, zf, lut, q, postWT, postb, out, lossAcc);
  hipLaunchKernelGGL(k_fin, dim3(1), dim3(256), 0, stream, lossAcc, counts, out_loss, out_perp);
}

// Round 3
// 266.278 us; speedup vs baseline: 1.9832x; 1.0944x over previous
//
#include <hip/hip_runtime.h>
#include <cstdint>

#define NB   64
#define ND   256
#define NHW  1024
#define NTOK 65536
#define NDC  128
#define NK   1024

#define OFF_LOSS 16777216
#define OFF_Q    16777217
#define OFF_PERP 16842753

#define GAPTHR 4e-3f
#define NEGINF (-3.402823466e38f)

typedef short short8 __attribute__((ext_vector_type(8)));
typedef float f32x4 __attribute__((ext_vector_type(4)));

__device__ __forceinline__ unsigned short f2bf(float f) {
  unsigned u = __float_as_uint(f);
  u += 0x7FFFu + ((u >> 16) & 1u);
  return (unsigned short)(u >> 16);
}
__device__ __forceinline__ float bf2f(unsigned short h) {
  return __uint_as_float(((unsigned)h) << 16);
}

__device__ __forceinline__ void gll16(const void* g, void* l) {
  __builtin_amdgcn_global_load_lds(
      (const __attribute__((address_space(1))) unsigned int*)g,
      (__attribute__((address_space(3))) unsigned int*)l, 16, 0, 0);
}

// ---------- init: bf16 splits (codebook for dist, preW/postW planes), norms, zeros ----------
__global__ __launch_bounds__(256) void k_init(
    const float* __restrict__ lut, const float* __restrict__ preW,
    const float* __restrict__ postW,
    unsigned short* __restrict__ ch,
    unsigned short* __restrict__ pwh, unsigned short* __restrict__ pwl,
    unsigned short* __restrict__ qwh, unsigned short* __restrict__ qwl,
    float* __restrict__ nhn, double* __restrict__ cn2d,
    int* __restrict__ counts, double* __restrict__ lossAcc, int* __restrict__ ctr) {
  int tid = blockIdx.x * 256 + threadIdx.x;
  int stride = gridDim.x * 256;
  for (int i = tid; i < NK * NDC; i += stride) {   // lut -> split bf16 ch[code][256] (dist)
    int code = i >> 7, c = i & 127;
    float f = lut[i];
    unsigned short h1 = f2bf(f);
    float r = f - bf2f(h1);
    ch[code * 256 + c] = h1;
    ch[code * 256 + 128 + c] = f2bf(r);
  }
  for (int i = tid; i < NDC * ND; i += stride) {   // preW [DC][D] -> trunc-split planes
    float f = preW[i];
    unsigned u = __float_as_uint(f);
    float lf = f - __uint_as_float(u & 0xffff0000u);
    pwh[i] = (unsigned short)(u >> 16);
    pwl[i] = (unsigned short)(__float_as_uint(lf) >> 16);
  }
  for (int i = tid; i < ND * NDC; i += stride) {   // postW [D][DC] -> trunc-split planes
    float f = postW[i];
    unsigned u = __float_as_uint(f);
    float lf = f - __uint_as_float(u & 0xffff0000u);
    qwh[i] = (unsigned short)(u >> 16);
    qwl[i] = (unsigned short)(__float_as_uint(lf) >> 16);
  }
  if (tid < NK) {
    float s = 0.f;
    double sd = 0.0;
    for (int c = 0; c < NDC; c++) {
      float v = lut[tid * NDC + c];
      s = fmaf(v, v, s);
      sd = fma((double)v, (double)v, sd);
    }
    nhn[tid] = -0.5f * s;
    cn2d[tid] = sd;
    counts[tid] = 0;
  }
  if (tid == 0) { *lossAcc = 0.0; *ctr = 0; }
}

// ---------- pre-conv via bf16-split MFMA: zf[n][dc] = sum_d x*preW + pre_b ----------
__global__ __launch_bounds__(256, 2) void k_preconv(
    const float* __restrict__ x, const unsigned short* __restrict__ pwh,
    const unsigned short* __restrict__ pwl, const float* __restrict__ pre_b,
    float* __restrict__ zf) {
  int bx = blockIdx.x;                       // 512 blocks: 128 tokens each
  int b = bx >> 3, p0 = (bx & 7) * 128;
  int tid = threadIdx.x;
  int lane = tid & 63, w = tid >> 6;
  int g = lane >> 4, l15 = lane & 15;
  const float* xb = x + (size_t)b * (ND * NHW);
  f32x4 acc[8][2];
  #pragma unroll
  for (int rt = 0; rt < 8; ++rt)
    #pragma unroll
    for (int ct = 0; ct < 2; ++ct) acc[rt][ct] = (f32x4){0.f, 0.f, 0.f, 0.f};

  for (int ks = 0; ks < 8; ++ks) {
    int k0 = ks * 32;
    short8 bh[2], bl[2];
    #pragma unroll
    for (int ct = 0; ct < 2; ++ct) {
      int p = p0 + w * 32 + ct * 16 + l15;
      float xv[8];
      #pragma unroll
      for (int j = 0; j < 8; ++j)
        xv[j] = xb[(k0 + g * 8 + j) * NHW + p];
      #pragma unroll
      for (int j = 0; j < 8; ++j) {
        unsigned u = __float_as_uint(xv[j]);
        float lf = xv[j] - __uint_as_float(u & 0xffff0000u);
        bh[ct][j] = (short)(u >> 16);
        bl[ct][j] = (short)(__float_as_uint(lf) >> 16);
      }
    }
    #pragma unroll
    for (int rt = 0; rt < 8; ++rt) {
      short8 ah = *reinterpret_cast<const short8*>(&pwh[(rt * 16 + l15) * ND + k0 + g * 8]);
      short8 al = *reinterpret_cast<const short8*>(&pwl[(rt * 16 + l15) * ND + k0 + g * 8]);
      #pragma unroll
      for (int ct = 0; ct < 2; ++ct) {
        acc[rt][ct] = __builtin_amdgcn_mfma_f32_16x16x32_bf16(ah, bh[ct], acc[rt][ct], 0, 0, 0);
        acc[rt][ct] = __builtin_amdgcn_mfma_f32_16x16x32_bf16(ah, bl[ct], acc[rt][ct], 0, 0, 0);
        acc[rt][ct] = __builtin_amdgcn_mfma_f32_16x16x32_bf16(al, bh[ct], acc[rt][ct], 0, 0, 0);
      }
    }
  }
  #pragma unroll
  for (int rt = 0; rt < 8; ++rt) {
    float4 bb = *reinterpret_cast<const float4*>(&pre_b[rt * 16 + g * 4]);
    #pragma unroll
    for (int ct = 0; ct < 2; ++ct) {
      int n = bx * 128 + w * 32 + ct * 16 + l15;
      float4 v;
      v.x = acc[rt][ct][0] + bb.x;
      v.y = acc[rt][ct][1] + bb.y;
      v.z = acc[rt][ct][2] + bb.z;
      v.w = acc[rt][ct][3] + bb.w;
      *reinterpret_cast<float4*>(&zf[(size_t)n * NDC + rt * 16 + g * 4]) = v;
    }
  }
}

// ---------- distance via bf16-split MFMA: argmax_k (z.c - 0.5|c|^2), flag near-ties ----------
__global__ __launch_bounds__(256, 2) void k_dist(
    const float* __restrict__ zf, const unsigned short* __restrict__ ch,
    const float* __restrict__ nhn,
    int* __restrict__ q, int* __restrict__ list, int* __restrict__ ctr) {
  __shared__ __align__(16) short chbuf[2][16384];   // 2 x 32 KB code chunk (swizzled image)
  __shared__ float HnLds[NK];                       // 4 KB (negated half-norms)
  int tid = threadIdx.x;
  int lane = tid & 63, w = tid >> 6;
  int g = lane >> 4;
  int n0 = blockIdx.x * 128;

  for (int i = tid; i < NK; i += 256) HnLds[i] = nhn[i];

  // A fragments: 32 tokens per wave, bf16-split in registers (z1 in [0..3], z2 in [4..7])
  short8 az[2][8];
  {
    int arow = lane & 15;
    #pragma unroll
    for (int rt = 0; rt < 2; ++rt) {
      const float* zr = zf + (size_t)(n0 + w * 32 + rt * 16 + arow) * NDC;
      #pragma unroll
      for (int f = 0; f < 4; ++f) {
        const float* p = zr + f * 32 + g * 8;
        float4 v0 = *reinterpret_cast<const float4*>(p);
        float4 v1 = *reinterpret_cast<const float4*>(p + 4);
        float vv[8] = {v0.x, v0.y, v0.z, v0.w, v1.x, v1.y, v1.z, v1.w};
        short8 hi, lo;
        #pragma unroll
        for (int j = 0; j < 8; ++j) {
          unsigned short h1 = f2bf(vv[j]);
          float r = vv[j] - bf2f(h1);
          hi[j] = (short)h1;
          lo[j] = (short)f2bf(r);
        }
        az[rt][f] = hi;
        az[rt][4 + f] = lo;
      }
    }
  }

  float best[2][4], sec[2][4];
  int bidx[2][4];
  #pragma unroll
  for (int rt = 0; rt < 2; ++rt)
    #pragma unroll
    for (int r = 0; r < 4; ++r) { best[rt][r] = NEGINF; sec[rt][r] = NEGINF; bidx[rt][r] = 0; }

  const char* chg = (const char*)ch;
  // stage chunk 0
  {
    const char* gb = chg + 0;
    #pragma unroll
    for (int rr = 0; rr < 8; ++rr) {
      int o = rr * 4096 + tid * 16;
      int so = o ^ (((o >> 9) & 7) << 4);
      gll16(gb + so, ((char*)&chbuf[0][0]) + o);
    }
  }
  asm volatile("s_waitcnt vmcnt(0)" ::: "memory");
  __syncthreads();

  int cur = 0;
  for (int chunk = 0; chunk < 16; ++chunk) {
    if (chunk < 15) {                         // prefetch next chunk into other buffer
      const char* gb = chg + (chunk + 1) * 32768;
      #pragma unroll
      for (int rr = 0; rr < 8; ++rr) {
        int o = rr * 4096 + tid * 16;
        int so = o ^ (((o >> 9) & 7) << 4);
        gll16(gb + so, ((char*)&chbuf[cur ^ 1][0]) + o);
      }
    }
    const char* cb = (const char*)&chbuf[cur][0];
    for (int ct = 0; ct < 4; ++ct) {
      int codeg = chunk * 64 + ct * 16 + (lane & 15);
      float nh = HnLds[codeg];
      short8 bc[8];
      #pragma unroll
      for (int f = 0; f < 8; ++f) {
        int byte = ((lane & 15) + ct * 16) * 512 + f * 64 + g * 16;
        byte ^= ((lane & 7) << 4);
        bc[f] = *reinterpret_cast<const short8*>(cb + byte);
      }
      f32x4 acc0 = {nh, nh, nh, nh};
      f32x4 acc1 = {nh, nh, nh, nh};
      #pragma unroll
      for (int j = 0; j < 4; ++j) {
        acc0 = __builtin_amdgcn_mfma_f32_16x16x32_bf16(az[0][j], bc[j], acc0, 0, 0, 0);
        acc1 = __builtin_amdgcn_mfma_f32_16x16x32_bf16(az[1][j], bc[j], acc1, 0, 0, 0);
        acc0 = __builtin_amdgcn_mfma_f32_16x16x32_bf16(az[0][j], bc[4 + j], acc0, 0, 0, 0);
        acc1 = __builtin_amdgcn_mfma_f32_16x16x32_bf16(az[1][j], bc[4 + j], acc1, 0, 0, 0);
        acc0 = __builtin_amdgcn_mfma_f32_16x16x32_bf16(az[0][4 + j], bc[j], acc0, 0, 0, 0);
        acc1 = __builtin_amdgcn_mfma_f32_16x16x32_bf16(az[1][4 + j], bc[j], acc1, 0, 0, 0);
      }
      #pragma unroll
      for (int r = 0; r < 4; ++r) {
        float s0 = acc0[r];
        bool t0 = s0 > best[0][r];
        bidx[0][r] = t0 ? codeg : bidx[0][r];
        sec[0][r] = fmaxf(sec[0][r], fminf(s0, best[0][r]));
        best[0][r] = fmaxf(s0, best[0][r]);
        float s1 = acc1[r];
        bool t1 = s1 > best[1][r];
        bidx[1][r] = t1 ? codeg : bidx[1][r];
        sec[1][r] = fmaxf(sec[1][r], fminf(s1, best[1][r]));
        best[1][r] = fmaxf(s1, best[1][r]);
      }
    }
    asm volatile("s_waitcnt vmcnt(0)" ::: "memory");
    __syncthreads();
    cur ^= 1;
  }

  // cross-lane merge over the 16 code-columns (lanes sharing g), then write
  #pragma unroll
  for (int rt = 0; rt < 2; ++rt) {
    #pragma unroll
    for (int r = 0; r < 4; ++r) {
      float b = best[rt][r];
      float s2 = sec[rt][r];
      int bi_ = bidx[rt][r];
      #pragma unroll
      for (int m = 1; m < 16; m <<= 1) {
        float ob = __shfl_xor(b, m, 64);
        float os = __shfl_xor(s2, m, 64);
        int oi = __shfl_xor(bi_, m, 64);
        float ns = fmaxf(fmaxf(s2, os), fminf(b, ob));
        bool take = (ob > b) || (ob == b && oi < bi_);
        b = take ? ob : b;
        bi_ = take ? oi : bi_;
        s2 = ns;
      }
      if ((lane & 15) == 0) {
        int token = n0 + w * 32 + rt * 16 + g * 4 + r;
        q[token] = bi_;
        if (b - s2 < GAPTHR) {
          int pos = atomicAdd(ctr, 1);
          list[pos] = token;
        }
      }
    }
  }
}

// ---------- rescore: f64 z recompute from x + full-codebook f64 argmin, 8 tokens/block ----------
__global__ __launch_bounds__(256) void k_rescore(
    const float* __restrict__ x, const float* __restrict__ preW,
    const float* __restrict__ pre_b, const float* __restrict__ lut,
    const double* __restrict__ cn2d,
    const int* __restrict__ list, const int* __restrict__ ctr, int* __restrict__ q) {
  __shared__ double zs[8][130];
  __shared__ double rd[8][256];
  __shared__ int rc[8][256];
  int nf = *ctr;
  int tid = threadIdx.x;
  int lane = tid & 63, w = tid >> 6;
  for (int t0 = blockIdx.x * 8; t0 < nf; t0 += gridDim.x * 8) {
    // phase 1: wave w computes f64 z for tokens t0 + w*2 + {0,1}
    for (int s = 0; s < 2; ++s) {
      int idx = t0 + w * 2 + s;
      int token = list[idx < nf ? idx : nf - 1];
      int b = token >> 10, p = token & 1023;
      double z0 = (double)pre_b[lane];
      double z1 = (double)pre_b[64 + lane];
      for (int db = 0; db < 4; ++db) {
        float xv = x[(size_t)(b * ND + db * 64 + lane) * NHW + p];
        const float* w0 = preW + (size_t)lane * ND + db * 64;
        const float* w1 = preW + (size_t)(64 + lane) * ND + db * 64;
        for (int j = 0; j < 64; ++j) {
          float xs = __shfl(xv, j, 64);
          z0 = fma((double)w0[j], (double)xs, z0);
          z1 = fma((double)w1[j], (double)xs, z1);
        }
      }
      zs[w * 2 + s][lane] = z0;
      zs[w * 2 + s][64 + lane] = z1;
    }
    __syncthreads();
    // phase 2: thread scans codes c = cc*256 + tid (ascending), 8 tokens each
    double bd[8]; int bci[8];
    #pragma unroll
    for (int t = 0; t < 8; ++t) { bd[t] = 1e300; bci[t] = 0x7fffffff; }
    for (int cc = 0; cc < 4; ++cc) {
      int c = cc * 256 + tid;
      const float* cr = lut + (size_t)c * NDC;
      double acc[8];
      #pragma unroll
      for (int t = 0; t < 8; ++t) acc[t] = 0.0;
      #pragma unroll 4
      for (int k = 0; k < NDC; ++k) {
        double lc = (double)cr[k];
        #pragma unroll
        for (int t = 0; t < 8; ++t) acc[t] = fma(zs[t][k], lc, acc[t]);
      }
      double cn = cn2d[c];
      #pragma unroll
      for (int t = 0; t < 8; ++t) {
        double d2 = cn - 2.0 * acc[t];          // |c|^2 - 2 z.c (argmin-equivalent)
        if (d2 < bd[t]) { bd[t] = d2; bci[t] = c; }
      }
    }
    #pragma unroll
    for (int t = 0; t < 8; ++t) { rd[t][tid] = bd[t]; rc[t][tid] = bci[t]; }
    __syncthreads();
    if (tid < 8) {
      int t = tid;
      double b_ = 1e300; int c_ = 0x7fffffff;
      for (int i = 0; i < 256; ++i) {
        double d = rd[t][i]; int c = rc[t][i];
        if (d < b_ || (d == b_ && c < c_)) { b_ = d; c_ = c; }
      }
      if (t0 + t < nf) q[list[t0 + t]] = c_;
    }
    __syncthreads();
  }
}

// ---------- post-conv via bf16-split MFMA + fused loss & histogram ----------
__global__ __launch_bounds__(256, 2) void k_post(
    const float* __restrict__ zf, const float* __restrict__ lut,
    const int* __restrict__ q, const unsigned short* __restrict__ qwh,
    const unsigned short* __restrict__ qwl, const float* __restrict__ post_b,
    float* __restrict__ out, double* __restrict__ lossAcc,
    int* __restrict__ counts, float* __restrict__ outq) {
  __shared__ float red[256];
  int bx = blockIdx.x;                       // 1024 blocks: (512 token sets) x (2 o-halves)
  int n0 = (bx >> 1) * 128;
  int oh = (bx & 1) * 128;
  int b = n0 >> 10, p0 = n0 & 1023;
  int tid = threadIdx.x;
  int lane = tid & 63, w = tid >> 6;
  int g = lane >> 4, l15 = lane & 15;

  int qv[2];
  #pragma unroll
  for (int ct = 0; ct < 2; ++ct) qv[ct] = q[n0 + w * 32 + ct * 16 + l15];

  f32x4 acc[8][2];
  #pragma unroll
  for (int rt = 0; rt < 8; ++rt)
    #pragma unroll
    for (int ct = 0; ct < 2; ++ct) acc[rt][ct] = (f32x4){0.f, 0.f, 0.f, 0.f};

  for (int ks = 0; ks < 4; ++ks) {
    int k0 = ks * 32;
    short8 bh[2], bl[2];
    #pragma unroll
    for (int ct = 0; ct < 2; ++ct) {
      const float* xr = lut + (size_t)qv[ct] * NDC + k0 + g * 8;
      float4 v0 = *reinterpret_cast<const float4*>(xr);
      float4 v1 = *reinterpret_cast<const float4*>(xr + 4);
      float vv[8] = {v0.x, v0.y, v0.z, v0.w, v1.x, v1.y, v1.z, v1.w};
      #pragma unroll
      for (int j = 0; j < 8; ++j) {
        unsigned u = __float_as_uint(vv[j]);
        float lf = vv[j] - __uint_as_float(u & 0xffff0000u);
        bh[ct][j] = (short)(u >> 16);
        bl[ct][j] = (short)(__float_as_uint(lf) >> 16);
      }
    }
    #pragma unroll
    for (int rt = 0; rt < 8; ++rt) {
      short8 ah = *reinterpret_cast<const short8*>(&qwh[(oh + rt * 16 + l15) * NDC + k0 + g * 8]);
      short8 al = *reinterpret_cast<const short8*>(&qwl[(oh + rt * 16 + l15) * NDC + k0 + g * 8]);
      #pragma unroll
      for (int ct = 0; ct < 2; ++ct) {
        acc[rt][ct] = __builtin_amdgcn_mfma_f32_16x16x32_bf16(ah, bh[ct], acc[rt][ct], 0, 0, 0);
        acc[rt][ct] = __builtin_amdgcn_mfma_f32_16x16x32_bf16(ah, bl[ct], acc[rt][ct], 0, 0, 0);
        acc[rt][ct] = __builtin_amdgcn_mfma_f32_16x16x32_bf16(al, bh[ct], acc[rt][ct], 0, 0, 0);
      }
    }
  }
  #pragma unroll
  for (int rt = 0; rt < 8; ++rt) {
    float4 bb = *reinterpret_cast<const float4*>(&post_b[oh + rt * 16 + g * 4]);
    float bv[4] = {bb.x, bb.y, bb.z, bb.w};
    #pragma unroll
    for (int ct = 0; ct < 2; ++ct) {
      int p = p0 + w * 32 + ct * 16 + l15;
      #pragma unroll
      for (int r = 0; r < 4; ++r) {
        int o = oh + rt * 16 + g * 4 + r;
        out[(size_t)(b * ND + o) * NHW + p] = acc[rt][ct][r] + bv[r];
      }
    }
  }
  // fused loss + histogram (only the oh==0 block of each token set)
  if (oh == 0) {
    if (tid < 128) {
      int n = n0 + tid;
      int c = q[n];
      atomicAdd(&counts[c], 1);
      outq[n] = (float)c;
    }
    float lp = 0.f;
    int t = tid >> 1, hf = tid & 1;
    int n = n0 + t;
    const float* zr = zf + (size_t)n * NDC + hf * 64;
    const float* cr = lut + (size_t)q[n] * NDC + hf * 64;
    #pragma unroll
    for (int i = 0; i < 16; ++i) {
      float4 zz = *reinterpret_cast<const float4*>(zr + i * 4);
      float4 xe = *reinterpret_cast<const float4*>(cr + i * 4);
      float d0 = zz.x - xe.x, d1 = zz.y - xe.y, d2 = zz.z - xe.z, d3 = zz.w - xe.w;
      lp += d0 * d0 + d1 * d1 + d2 * d2 + d3 * d3;
    }
    red[tid] = lp;
    __syncthreads();
    for (int s = 128; s > 0; s >>= 1) {
      if (tid < s) red[tid] += red[tid + s];
      __syncthreads();
    }
    if (tid == 0) atomicAdd(lossAcc, (double)red[0]);
  }
}

// ---------- finalize ----------
__global__ __launch_bounds__(256) void k_fin(
    const double* __restrict__ lossAcc, const int* __restrict__ counts,
    float* __restrict__ out_loss, float* __restrict__ out_perp) {
  __shared__ float red[256];
  int tid = threadIdx.x;
  float h = 0.f;
  for (int i = tid; i < NK; i += 256) {
    float e = (float)counts[i] * (1.0f / (float)NTOK);
    h += e * logf(e + 1e-10f);
  }
  red[tid] = h;
  __syncthreads();
  for (int s = 128; s > 0; s >>= 1) {
    if (tid < s) red[tid] += red[tid + s];
    __syncthreads();
  }
  if (tid == 0) {
    *out_perp = expf(-red[0]);
    *out_loss = (float)(*lossAcc / ((double)NTOK * (double)NDC));
  }
}

extern "C" void kernel_launch(void* const* d_in, const int* in_sizes, int n_in,
                              void* d_out, int out_size, void* d_ws, size_t ws_size,
                              hipStream_t stream) {
  const float* x     = (const float*)d_in[0];
  const float* preW  = (const float*)d_in[1];
  const float* preb  = (const float*)d_in[2];
  const float* postW = (const float*)d_in[3];
  const float* postb = (const float*)d_in[4];
  const float* lut   = (const float*)d_in[5];
  float* out = (float*)d_out;

  char* ws = (char*)d_ws;
  float*          zf      = (float*)(ws);                      // 33,554,432 B
  unsigned short* ch      = (unsigned short*)(ws + 33554432);  //   524,288 B
  unsigned short* pwh     = (unsigned short*)(ws + 34078720);  //    65,536 B
  unsigned short* pwl     = (unsigned short*)(ws + 34144256);  //    65,536 B
  unsigned short* qwh     = (unsigned short*)(ws + 34209792);  //    65,536 B
  unsigned short* qwl     = (unsigned short*)(ws + 34275328);  //    65,536 B
  float*          nhn     = (float*)(ws + 34340864);           //     4,096 B
  int*            q       = (int*)  (ws + 34344960);           //   262,144 B
  int*            list    = (int*)  (ws + 34607104);           //   262,144 B
  int*            counts  = (int*)  (ws + 34869248);           //     4,096 B
  double*         lossAcc = (double*)(ws + 34873344);          //         8 B
  int*            ctr     = (int*)  (ws + 34873352);           //         4 B
  double*         cn2d    = (double*)(ws + 34873360);          //     8,192 B

  float* out_loss = out + OFF_LOSS;
  float* out_q    = out + OFF_Q;
  float* out_perp = out + OFF_PERP;

  hipLaunchKernelGGL(k_init, dim3(512), dim3(256), 0, stream,
                     lut, preW, postW, ch, pwh, pwl, qwh, qwl, nhn, cn2d,
                     counts, lossAcc, ctr);
  hipLaunchKernelGGL(k_preconv, dim3(512), dim3(256), 0, stream, x, pwh, pwl, preb, zf);
  hipLaunchKernelGGL(k_dist, dim3(512), dim3(256), 0, stream, zf, ch, nhn, q, list, ctr);
  hipLaunchKernelGGL(k_rescore, dim3(256), dim3(256), 0, stream,
                     x, preW, preb, lut, cn2d, list, ctr, q);
  hipLaunchKernelGGL(k_post, dim3(1024), dim3(256), 0, stream,
                     zf, lut, q, qwh, qwl, postb, out, lossAcc, counts, out_q);
  hipLaunchKernelGGL(k_fin, dim3(1), dim3(256), 0, stream, lossAcc, counts, out_loss, out_perp);
}

// Round 4
// 220.218 us; speedup vs baseline: 2.3979x; 1.2092x over previous
//
#include <hip/hip_runtime.h>
#include <cstdint>

#define NB   64
#define ND   256
#define NHW  1024
#define NTOK 65536
#define NDC  128
#define NK   1024

#define OFF_LOSS 16777216
#define OFF_Q    16777217
#define OFF_PERP 16842753

#define GAPTHR 1e-3f
#define NEGINF (-3.402823466e38f)

typedef short short8 __attribute__((ext_vector_type(8)));
typedef float f32x4 __attribute__((ext_vector_type(4)));

__device__ __forceinline__ unsigned short f2bf(float f) {
  unsigned u = __float_as_uint(f);
  u += 0x7FFFu + ((u >> 16) & 1u);
  return (unsigned short)(u >> 16);
}
__device__ __forceinline__ float bf2f(unsigned short h) {
  return __uint_as_float(((unsigned)h) << 16);
}

__device__ __forceinline__ void gll16(const void* g, void* l) {
  __builtin_amdgcn_global_load_lds(
      (const __attribute__((address_space(1))) unsigned int*)g,
      (__attribute__((address_space(3))) unsigned int*)l, 16, 0, 0);
}

// ---------- init: bf16 splits (codebook for dist, preW/postW planes), norms, zeros ----------
__global__ __launch_bounds__(256) void k_init(
    const float* __restrict__ lut, const float* __restrict__ preW,
    const float* __restrict__ postW,
    unsigned short* __restrict__ ch,
    unsigned short* __restrict__ pwh, unsigned short* __restrict__ pwl,
    unsigned short* __restrict__ qwh, unsigned short* __restrict__ qwl,
    float* __restrict__ nhn, double* __restrict__ cn2d,
    int* __restrict__ counts, double* __restrict__ lossAcc, int* __restrict__ ctr) {
  int tid = blockIdx.x * 256 + threadIdx.x;
  int stride = gridDim.x * 256;
  for (int i = tid; i < NK * NDC; i += stride) {   // lut -> split bf16 ch[code][256] (dist)
    int code = i >> 7, c = i & 127;
    float f = lut[i];
    unsigned short h1 = f2bf(f);
    float r = f - bf2f(h1);
    ch[code * 256 + c] = h1;
    ch[code * 256 + 128 + c] = f2bf(r);
  }
  for (int i = tid; i < NDC * ND; i += stride) {   // preW [DC][D] -> trunc-split planes
    float f = preW[i];
    unsigned u = __float_as_uint(f);
    float lf = f - __uint_as_float(u & 0xffff0000u);
    pwh[i] = (unsigned short)(u >> 16);
    pwl[i] = (unsigned short)(__float_as_uint(lf) >> 16);
  }
  for (int i = tid; i < ND * NDC; i += stride) {   // postW [D][DC] -> trunc-split planes
    float f = postW[i];
    unsigned u = __float_as_uint(f);
    float lf = f - __uint_as_float(u & 0xffff0000u);
    qwh[i] = (unsigned short)(u >> 16);
    qwl[i] = (unsigned short)(__float_as_uint(lf) >> 16);
  }
  if (tid < NK) {
    float s = 0.f;
    double sd = 0.0;
    for (int c = 0; c < NDC; c++) {
      float v = lut[tid * NDC + c];
      s = fmaf(v, v, s);
      sd = fma((double)v, (double)v, sd);
    }
    nhn[tid] = -0.5f * s;
    cn2d[tid] = sd;
    counts[tid] = 0;
  }
  if (tid == 0) { *lossAcc = 0.0; *ctr = 0; }
}

// ---------- pre-conv via bf16-split MFMA: zf[n][dc] = sum_d x*preW + pre_b ----------
__global__ __launch_bounds__(256, 2) void k_preconv(
    const float* __restrict__ x, const unsigned short* __restrict__ pwh,
    const unsigned short* __restrict__ pwl, const float* __restrict__ pre_b,
    float* __restrict__ zf) {
  int bx = blockIdx.x;                       // 512 blocks: 128 tokens each
  int b = bx >> 3, p0 = (bx & 7) * 128;
  int tid = threadIdx.x;
  int lane = tid & 63, w = tid >> 6;
  int g = lane >> 4, l15 = lane & 15;
  const float* xb = x + (size_t)b * (ND * NHW);
  f32x4 acc[8][2];
  #pragma unroll
  for (int rt = 0; rt < 8; ++rt)
    #pragma unroll
    for (int ct = 0; ct < 2; ++ct) acc[rt][ct] = (f32x4){0.f, 0.f, 0.f, 0.f};

  for (int ks = 0; ks < 8; ++ks) {
    int k0 = ks * 32;
    short8 bh[2], bl[2];
    #pragma unroll
    for (int ct = 0; ct < 2; ++ct) {
      int p = p0 + w * 32 + ct * 16 + l15;
      float xv[8];
      #pragma unroll
      for (int j = 0; j < 8; ++j)
        xv[j] = xb[(k0 + g * 8 + j) * NHW + p];
      #pragma unroll
      for (int j = 0; j < 8; ++j) {
        unsigned u = __float_as_uint(xv[j]);
        float lf = xv[j] - __uint_as_float(u & 0xffff0000u);
        bh[ct][j] = (short)(u >> 16);
        bl[ct][j] = (short)(__float_as_uint(lf) >> 16);
      }
    }
    #pragma unroll
    for (int rt = 0; rt < 8; ++rt) {
      short8 ah = *reinterpret_cast<const short8*>(&pwh[(rt * 16 + l15) * ND + k0 + g * 8]);
      short8 al = *reinterpret_cast<const short8*>(&pwl[(rt * 16 + l15) * ND + k0 + g * 8]);
      #pragma unroll
      for (int ct = 0; ct < 2; ++ct) {
        acc[rt][ct] = __builtin_amdgcn_mfma_f32_16x16x32_bf16(ah, bh[ct], acc[rt][ct], 0, 0, 0);
        acc[rt][ct] = __builtin_amdgcn_mfma_f32_16x16x32_bf16(ah, bl[ct], acc[rt][ct], 0, 0, 0);
        acc[rt][ct] = __builtin_amdgcn_mfma_f32_16x16x32_bf16(al, bh[ct], acc[rt][ct], 0, 0, 0);
      }
    }
  }
  #pragma unroll
  for (int rt = 0; rt < 8; ++rt) {
    float4 bb = *reinterpret_cast<const float4*>(&pre_b[rt * 16 + g * 4]);
    #pragma unroll
    for (int ct = 0; ct < 2; ++ct) {
      int n = bx * 128 + w * 32 + ct * 16 + l15;
      float4 v;
      v.x = acc[rt][ct][0] + bb.x;
      v.y = acc[rt][ct][1] + bb.y;
      v.z = acc[rt][ct][2] + bb.z;
      v.w = acc[rt][ct][3] + bb.w;
      *reinterpret_cast<float4*>(&zf[(size_t)n * NDC + rt * 16 + g * 4]) = v;
    }
  }
}

// ---------- distance via bf16-split MFMA: argmax_k (z.c - 0.5|c|^2), flag near-ties ----------
__global__ __launch_bounds__(256, 2) void k_dist(
    const float* __restrict__ zf, const unsigned short* __restrict__ ch,
    const float* __restrict__ nhn,
    int* __restrict__ q, int* __restrict__ list, int* __restrict__ ctr) {
  __shared__ __align__(16) short chbuf[2][16384];   // 2 x 32 KB code chunk (swizzled image)
  __shared__ float HnLds[NK];                       // 4 KB (negated half-norms)
  int tid = threadIdx.x;
  int lane = tid & 63, w = tid >> 6;
  int g = lane >> 4;
  int n0 = blockIdx.x * 128;

  for (int i = tid; i < NK; i += 256) HnLds[i] = nhn[i];

  // A fragments: 32 tokens per wave, bf16-split in registers (z1 in [0..3], z2 in [4..7])
  short8 az[2][8];
  {
    int arow = lane & 15;
    #pragma unroll
    for (int rt = 0; rt < 2; ++rt) {
      const float* zr = zf + (size_t)(n0 + w * 32 + rt * 16 + arow) * NDC;
      #pragma unroll
      for (int f = 0; f < 4; ++f) {
        const float* p = zr + f * 32 + g * 8;
        float4 v0 = *reinterpret_cast<const float4*>(p);
        float4 v1 = *reinterpret_cast<const float4*>(p + 4);
        float vv[8] = {v0.x, v0.y, v0.z, v0.w, v1.x, v1.y, v1.z, v1.w};
        short8 hi, lo;
        #pragma unroll
        for (int j = 0; j < 8; ++j) {
          unsigned short h1 = f2bf(vv[j]);
          float r = vv[j] - bf2f(h1);
          hi[j] = (short)h1;
          lo[j] = (short)f2bf(r);
        }
        az[rt][f] = hi;
        az[rt][4 + f] = lo;
      }
    }
  }

  float best[2][4], sec[2][4];
  int bidx[2][4];
  #pragma unroll
  for (int rt = 0; rt < 2; ++rt)
    #pragma unroll
    for (int r = 0; r < 4; ++r) { best[rt][r] = NEGINF; sec[rt][r] = NEGINF; bidx[rt][r] = 0; }

  const char* chg = (const char*)ch;
  // stage chunk 0
  {
    const char* gb = chg + 0;
    #pragma unroll
    for (int rr = 0; rr < 8; ++rr) {
      int o = rr * 4096 + tid * 16;
      int so = o ^ (((o >> 9) & 7) << 4);
      gll16(gb + so, ((char*)&chbuf[0][0]) + o);
    }
  }
  asm volatile("s_waitcnt vmcnt(0)" ::: "memory");
  __syncthreads();

  int cur = 0;
  for (int chunk = 0; chunk < 16; ++chunk) {
    if (chunk < 15) {                         // prefetch next chunk into other buffer
      const char* gb = chg + (chunk + 1) * 32768;
      #pragma unroll
      for (int rr = 0; rr < 8; ++rr) {
        int o = rr * 4096 + tid * 16;
        int so = o ^ (((o >> 9) & 7) << 4);
        gll16(gb + so, ((char*)&chbuf[cur ^ 1][0]) + o);
      }
    }
    const char* cb = (const char*)&chbuf[cur][0];
    for (int ct = 0; ct < 4; ++ct) {
      int codeg = chunk * 64 + ct * 16 + (lane & 15);
      float nh = HnLds[codeg];
      short8 bc[8];
      #pragma unroll
      for (int f = 0; f < 8; ++f) {
        int byte = ((lane & 15) + ct * 16) * 512 + f * 64 + g * 16;
        byte ^= ((lane & 7) << 4);
        bc[f] = *reinterpret_cast<const short8*>(cb + byte);
      }
      f32x4 acc0 = {nh, nh, nh, nh};
      f32x4 acc1 = {nh, nh, nh, nh};
      #pragma unroll
      for (int j = 0; j < 4; ++j) {
        acc0 = __builtin_amdgcn_mfma_f32_16x16x32_bf16(az[0][j], bc[j], acc0, 0, 0, 0);
        acc1 = __builtin_amdgcn_mfma_f32_16x16x32_bf16(az[1][j], bc[j], acc1, 0, 0, 0);
        acc0 = __builtin_amdgcn_mfma_f32_16x16x32_bf16(az[0][j], bc[4 + j], acc0, 0, 0, 0);
        acc1 = __builtin_amdgcn_mfma_f32_16x16x32_bf16(az[1][j], bc[4 + j], acc1, 0, 0, 0);
        acc0 = __builtin_amdgcn_mfma_f32_16x16x32_bf16(az[0][4 + j], bc[j], acc0, 0, 0, 0);
        acc1 = __builtin_amdgcn_mfma_f32_16x16x32_bf16(az[1][4 + j], bc[j], acc1, 0, 0, 0);
      }
      #pragma unroll
      for (int r = 0; r < 4; ++r) {
        float s0 = acc0[r];
        bool t0 = s0 > best[0][r];
        bidx[0][r] = t0 ? codeg : bidx[0][r];
        sec[0][r] = fmaxf(sec[0][r], fminf(s0, best[0][r]));
        best[0][r] = fmaxf(s0, best[0][r]);
        float s1 = acc1[r];
        bool t1 = s1 > best[1][r];
        bidx[1][r] = t1 ? codeg : bidx[1][r];
        sec[1][r] = fmaxf(sec[1][r], fminf(s1, best[1][r]));
        best[1][r] = fmaxf(s1, best[1][r]);
      }
    }
    asm volatile("s_waitcnt vmcnt(0)" ::: "memory");
    __syncthreads();
    cur ^= 1;
  }

  // cross-lane merge over the 16 code-columns (lanes sharing g), then write
  #pragma unroll
  for (int rt = 0; rt < 2; ++rt) {
    #pragma unroll
    for (int r = 0; r < 4; ++r) {
      float b = best[rt][r];
      float s2 = sec[rt][r];
      int bi_ = bidx[rt][r];
      #pragma unroll
      for (int m = 1; m < 16; m <<= 1) {
        float ob = __shfl_xor(b, m, 64);
        float os = __shfl_xor(s2, m, 64);
        int oi = __shfl_xor(bi_, m, 64);
        float ns = fmaxf(fmaxf(s2, os), fminf(b, ob));
        bool take = (ob > b) || (ob == b && oi < bi_);
        b = take ? ob : b;
        bi_ = take ? oi : bi_;
        s2 = ns;
      }
      if ((lane & 15) == 0) {
        int token = n0 + w * 32 + rt * 16 + g * 4 + r;
        q[token] = bi_;
        if (b - s2 < GAPTHR) {
          int pos = atomicAdd(ctr, 1);
          list[pos] = token;
        }
      }
    }
  }
}

// ---------- rescore v3: 4 tokens/block-iter, fully thread-parallel f64 ----------
__global__ __launch_bounds__(256) void k_rescore(
    const float* __restrict__ x, const float* __restrict__ preW,
    const float* __restrict__ pre_b, const float* __restrict__ lut,
    const double* __restrict__ cn2d,
    const int* __restrict__ list, const int* __restrict__ ctr, int* __restrict__ q) {
  __shared__ float xs[4][256];
  __shared__ double zs[4][128];
  __shared__ double rd[4][256];
  __shared__ int    rc[4][256];
  int nf = *ctr;
  int tid = threadIdx.x;
  int w = tid >> 6, lane = tid & 63;
  for (int g0 = blockIdx.x * 4; g0 < nf; g0 += gridDim.x * 4) {
    int nt = nf - g0; if (nt > 4) nt = 4;
    // phase 0: stage the 4 x-columns (d = tid)
    #pragma unroll
    for (int t = 0; t < 4; ++t) {
      int token = list[g0 + (t < nt ? t : 0)];
      int b = token >> 10, p = token & 1023;
      xs[t][tid] = x[(size_t)(b * ND + tid) * NHW + p];
    }
    __syncthreads();
    // phase 1: z in f64 — 512 (token,dc) tasks over 256 threads x 2 reps
    #pragma unroll
    for (int rep = 0; rep < 2; ++rep) {
      int idx = rep * 256 + tid;
      int t = idx >> 7, dc = idx & 127;
      double acc = (double)pre_b[dc];
      const float* wr = preW + (size_t)dc * ND;
      #pragma unroll 4
      for (int d = 0; d < ND; d += 4) {
        float4 wv = *reinterpret_cast<const float4*>(wr + d);
        acc = fma((double)wv.x, (double)xs[t][d + 0], acc);
        acc = fma((double)wv.y, (double)xs[t][d + 1], acc);
        acc = fma((double)wv.z, (double)xs[t][d + 2], acc);
        acc = fma((double)wv.w, (double)xs[t][d + 3], acc);
      }
      zs[t][dc] = acc;
    }
    __syncthreads();
    // phase 2: each thread scans 4 codes (ascending) for all 4 tokens
    double bd[4]; int bc_[4];
    #pragma unroll
    for (int t = 0; t < 4; ++t) { bd[t] = 1e300; bc_[t] = 0x7fffffff; }
    for (int cc = 0; cc < 4; ++cc) {
      int c = cc * 256 + tid;
      const float* cr = lut + (size_t)c * NDC;
      double a0 = 0.0, a1 = 0.0, a2 = 0.0, a3 = 0.0;
      #pragma unroll 4
      for (int k = 0; k < NDC; ++k) {
        double lc = (double)cr[k];
        a0 = fma(zs[0][k], lc, a0);
        a1 = fma(zs[1][k], lc, a1);
        a2 = fma(zs[2][k], lc, a2);
        a3 = fma(zs[3][k], lc, a3);
      }
      double cn = cn2d[c];
      double d0 = cn - 2.0 * a0; if (d0 < bd[0]) { bd[0] = d0; bc_[0] = c; }
      double d1 = cn - 2.0 * a1; if (d1 < bd[1]) { bd[1] = d1; bc_[1] = c; }
      double d2 = cn - 2.0 * a2; if (d2 < bd[2]) { bd[2] = d2; bc_[2] = c; }
      double d3 = cn - 2.0 * a3; if (d3 < bd[3]) { bd[3] = d3; bc_[3] = c; }
    }
    #pragma unroll
    for (int t = 0; t < 4; ++t) { rd[t][tid] = bd[t]; rc[t][tid] = bc_[t]; }
    __syncthreads();
    // phase 3: wave w reduces token w (tree, lowest-index tie-break)
    {
      double b_ = rd[w][lane]; int c_ = rc[w][lane];
      #pragma unroll
      for (int s = 64; s < 256; s += 64) {
        double ob = rd[w][lane + s]; int oc = rc[w][lane + s];
        if (ob < b_ || (ob == b_ && oc < c_)) { b_ = ob; c_ = oc; }
      }
      #pragma unroll
      for (int m = 1; m < 64; m <<= 1) {
        double ob = __shfl_xor(b_, m, 64);
        int oc = __shfl_xor(c_, m, 64);
        if (ob < b_ || (ob == b_ && oc < c_)) { b_ = ob; c_ = oc; }
      }
      if (lane == 0 && w < nt) q[list[g0 + w]] = c_;
    }
    __syncthreads();
  }
}

// ---------- post-conv via bf16-split MFMA + fused loss & histogram ----------
__global__ __launch_bounds__(256, 2) void k_post(
    const float* __restrict__ zf, const float* __restrict__ lut,
    const int* __restrict__ q, const unsigned short* __restrict__ qwh,
    const unsigned short* __restrict__ qwl, const float* __restrict__ post_b,
    float* __restrict__ out, double* __restrict__ lossAcc,
    int* __restrict__ counts, float* __restrict__ outq) {
  __shared__ float red[256];
  int bx = blockIdx.x;                       // 1024 blocks: (512 token sets) x (2 o-halves)
  int n0 = (bx >> 1) * 128;
  int oh = (bx & 1) * 128;
  int b = n0 >> 10, p0 = n0 & 1023;
  int tid = threadIdx.x;
  int lane = tid & 63, w = tid >> 6;
  int g = lane >> 4, l15 = lane & 15;

  int qv[2];
  #pragma unroll
  for (int ct = 0; ct < 2; ++ct) qv[ct] = q[n0 + w * 32 + ct * 16 + l15];

  f32x4 acc[8][2];
  #pragma unroll
  for (int rt = 0; rt < 8; ++rt)
    #pragma unroll
    for (int ct = 0; ct < 2; ++ct) acc[rt][ct] = (f32x4){0.f, 0.f, 0.f, 0.f};

  for (int ks = 0; ks < 4; ++ks) {
    int k0 = ks * 32;
    short8 bh[2], bl[2];
    #pragma unroll
    for (int ct = 0; ct < 2; ++ct) {
      const float* xr = lut + (size_t)qv[ct] * NDC + k0 + g * 8;
      float4 v0 = *reinterpret_cast<const float4*>(xr);
      float4 v1 = *reinterpret_cast<const float4*>(xr + 4);
      float vv[8] = {v0.x, v0.y, v0.z, v0.w, v1.x, v1.y, v1.z, v1.w};
      #pragma unroll
      for (int j = 0; j < 8; ++j) {
        unsigned u = __float_as_uint(vv[j]);
        float lf = vv[j] - __uint_as_float(u & 0xffff0000u);
        bh[ct][j] = (short)(u >> 16);
        bl[ct][j] = (short)(__float_as_uint(lf) >> 16);
      }
    }
    #pragma unroll
    for (int rt = 0; rt < 8; ++rt) {
      short8 ah = *reinterpret_cast<const short8*>(&qwh[(oh + rt * 16 + l15) * NDC + k0 + g * 8]);
      short8 al = *reinterpret_cast<const short8*>(&qwl[(oh + rt * 16 + l15) * NDC + k0 + g * 8]);
      #pragma unroll
      for (int ct = 0; ct < 2; ++ct) {
        acc[rt][ct] = __builtin_amdgcn_mfma_f32_16x16x32_bf16(ah, bh[ct], acc[rt][ct], 0, 0, 0);
        acc[rt][ct] = __builtin_amdgcn_mfma_f32_16x16x32_bf16(ah, bl[ct], acc[rt][ct], 0, 0, 0);
        acc[rt][ct] = __builtin_amdgcn_mfma_f32_16x16x32_bf16(al, bh[ct], acc[rt][ct], 0, 0, 0);
      }
    }
  }
  #pragma unroll
  for (int rt = 0; rt < 8; ++rt) {
    float4 bb = *reinterpret_cast<const float4*>(&post_b[oh + rt * 16 + g * 4]);
    float bv[4] = {bb.x, bb.y, bb.z, bb.w};
    #pragma unroll
    for (int ct = 0; ct < 2; ++ct) {
      int p = p0 + w * 32 + ct * 16 + l15;
      #pragma unroll
      for (int r = 0; r < 4; ++r) {
        int o = oh + rt * 16 + g * 4 + r;
        out[(size_t)(b * ND + o) * NHW + p] = acc[rt][ct][r] + bv[r];
      }
    }
  }
  // fused loss + histogram (only the oh==0 block of each token set)
  if (oh == 0) {
    if (tid < 128) {
      int n = n0 + tid;
      int c = q[n];
      atomicAdd(&counts[c], 1);
      outq[n] = (float)c;
    }
    float lp = 0.f;
    int t = tid >> 1, hf = tid & 1;
    int n = n0 + t;
    const float* zr = zf + (size_t)n * NDC + hf * 64;
    const float* cr = lut + (size_t)q[n] * NDC + hf * 64;
    #pragma unroll
    for (int i = 0; i < 16; ++i) {
      float4 zz = *reinterpret_cast<const float4*>(zr + i * 4);
      float4 xe = *reinterpret_cast<const float4*>(cr + i * 4);
      float d0 = zz.x - xe.x, d1 = zz.y - xe.y, d2 = zz.z - xe.z, d3 = zz.w - xe.w;
      lp += d0 * d0 + d1 * d1 + d2 * d2 + d3 * d3;
    }
    red[tid] = lp;
    __syncthreads();
    for (int s = 128; s > 0; s >>= 1) {
      if (tid < s) red[tid] += red[tid + s];
      __syncthreads();
    }
    if (tid == 0) atomicAdd(lossAcc, (double)red[0]);
  }
}

// ---------- finalize ----------
__global__ __launch_bounds__(256) void k_fin(
    const double* __restrict__ lossAcc, const int* __restrict__ counts,
    float* __restrict__ out_loss, float* __restrict__ out_perp) {
  __shared__ float red[256];
  int tid = threadIdx.x;
  float h = 0.f;
  for (int i = tid; i < NK; i += 256) {
    float e = (float)counts[i] * (1.0f / (float)NTOK);
    h += e * logf(e + 1e-10f);
  }
  red[tid] = h;
  __syncthreads();
  for (int s = 128; s > 0; s >>= 1) {
    if (tid < s) red[tid] += red[tid + s];
    __syncthreads();
  }
  if (tid == 0) {
    *out_perp = expf(-red[0]);
    *out_loss = (float)(*lossAcc / ((double)NTOK * (double)NDC));
  }
}

extern "C" void kernel_launch(void* const* d_in, const int* in_sizes, int n_in,
                              void* d_out, int out_size, void* d_ws, size_t ws_size,
                              hipStream_t stream) {
  const float* x     = (const float*)d_in[0];
  const float* preW  = (const float*)d_in[1];
  const float* preb  = (const float*)d_in[2];
  const float* postW = (const float*)d_in[3];
  const float* postb = (const float*)d_in[4];
  const float* lut   = (const float*)d_in[5];
  float* out = (float*)d_out;

  char* ws = (char*)d_ws;
  float*          zf      = (float*)(ws);                      // 33,554,432 B
  unsigned short* ch      = (unsigned short*)(ws + 33554432);  //   524,288 B
  unsigned short* pwh     = (unsigned short*)(ws + 34078720);  //    65,536 B
  unsigned short* pwl     = (unsigned short*)(ws + 34144256);  //    65,536 B
  unsigned short* qwh     = (unsigned short*)(ws + 34209792);  //    65,536 B
  unsigned short* qwl     = (unsigned short*)(ws + 34275328);  //    65,536 B
  float*          nhn     = (float*)(ws + 34340864);           //     4,096 B
  int*            q       = (int*)  (ws + 34344960);           //   262,144 B
  int*            list    = (int*)  (ws + 34607104);           //   262,144 B
  int*            counts  = (int*)  (ws + 34869248);           //     4,096 B
  double*         lossAcc = (double*)(ws + 34873344);          //         8 B
  int*            ctr     = (int*)  (ws + 34873352);           //         4 B
  double*         cn2d    = (double*)(ws + 34873360);          //     8,192 B

  float* out_loss = out + OFF_LOSS;
  float* out_q    = out + OFF_Q;
  float* out_perp = out + OFF_PERP;

  hipLaunchKernelGGL(k_init, dim3(512), dim3(256), 0, stream,
                     lut, preW, postW, ch, pwh, pwl, qwh, qwl, nhn, cn2d,
                     counts, lossAcc, ctr);
  hipLaunchKernelGGL(k_preconv, dim3(512), dim3(256), 0, stream, x, pwh, pwl, preb, zf);
  hipLaunchKernelGGL(k_dist, dim3(512), dim3(256), 0, stream, zf, ch, nhn, q, list, ctr);
  hipLaunchKernelGGL(k_rescore, dim3(1024), dim3(256), 0, stream,
                     x, preW, preb, lut, cn2d, list, ctr, q);
  hipLaunchKernelGGL(k_post, dim3(1024), dim3(256), 0, stream,
                     zf, lut, q, qwh, qwl, postb, out, lossAcc, counts, out_q);
  hipLaunchKernelGGL(k_fin, dim3(1), dim3(256), 0, stream, lossAcc, counts, out_loss, out_perp);
}